// Round 6
// baseline (213.484 us; speedup 1.0000x reference)
//
#include <hip/hip_runtime.h>

#define HH 16
#define DKK 64
#define SS 2048
#define BB 2
#define DD 1024

typedef __attribute__((ext_vector_type(4))) float f32x4;
typedef __attribute__((ext_vector_type(16))) float f32x16;
typedef __attribute__((ext_vector_type(8))) short bf16x8;
typedef __attribute__((ext_vector_type(4))) short s16x4;
typedef __attribute__((ext_vector_type(4))) int i32x4;

#define WAITCNT_VM0 0xF70  // vmcnt(0), ignore exp/lgkm

__device__ __forceinline__ short bf16b(float f) {
    union { float f; unsigned u; } x; x.f = f;
    unsigned r = (x.u + 0x7fffu + ((x.u >> 16) & 1u)) >> 16;
    return (short)r;
}

__device__ __forceinline__ f32x4 mfma16(bf16x8 a, bf16x8 b, f32x4 c) {
    return __builtin_amdgcn_mfma_f32_16x16x32_bf16(a, b, c, 0, 0, 0);
}

__device__ __forceinline__ f32x16 mfma32(bf16x8 a, bf16x8 b, f32x16 c) {
    return __builtin_amdgcn_mfma_f32_32x32x16_bf16(a, b, c, 0, 0, 0);
}

__device__ __forceinline__ void lds16(const short* g, short* l) {
    __builtin_amdgcn_global_load_lds(
        (const __attribute__((address_space(1))) void*)g,
        (__attribute__((address_space(3))) void*)l, 16, 0, 0);
}

// pack 2 f32 -> 1 dword of 2 bf16 (RNE)
__device__ __forceinline__ int cvtpk(float lo, float hi) {
    int r;
    asm("v_cvt_pk_bf16_f32 %0, %1, %2" : "=v"(r) : "v"(lo), "v"(hi));
    return r;
}

// swap a's upper 32 lanes with b's lower 32 lanes
__device__ __forceinline__ void swap32(int& a, int& b) {
    asm("v_permlane32_swap_b32 %0, %1" : "+v"(a), "+v"(b));
}

// ---------------- merged prologue: cast + transpose + bias in ONE launch ----------------
// blocks [0,4096): hs fp32->bf16; [4096,8192): weight transpose; [8192,8448): bias.
__global__ __launch_bounds__(256) void prep(
    const float* __restrict__ hs,
    const float* __restrict__ W0, const float* __restrict__ W1,
    const float* __restrict__ W2, const float* __restrict__ W3,
    const float* __restrict__ rb,
    short* __restrict__ hsb,
    short* __restrict__ T0, short* __restrict__ T1,
    short* __restrict__ T2, short* __restrict__ T3,
    float* __restrict__ tab) {
    __shared__ short tile[32][33];
    int blk = blockIdx.x, tid = threadIdx.x;
    if (blk < 4096) {
        int i = (blk * 256 + tid) * 4;
        f32x4 v = *(const f32x4*)(hs + i);
        s16x4 o;
        o.x = bf16b(v.x); o.y = bf16b(v.y); o.z = bf16b(v.z); o.w = bf16b(v.w);
        *(s16x4*)(hsb + i) = o;
    } else if (blk < 8192) {
        int t = blk - 4096;
        int z = t >> 10, r = t & 1023;
        int bx = r & 31, by = r >> 5;
        const float* W; short* T;
        switch (z) {
            case 0: W = W0; T = T0; break;
            case 1: W = W1; T = T1; break;
            case 2: W = W2; T = T2; break;
            default: W = W3; T = T3; break;
        }
        int n0 = bx * 32, k0 = by * 32;
        int tx = tid & 31, ty = (tid >> 5) * 4;
#pragma unroll
        for (int i = 0; i < 4; i++)
            tile[ty + i][tx] = bf16b(W[(k0 + ty + i) * DD + n0 + tx]);
        __syncthreads();
#pragma unroll
        for (int i = 0; i < 4; i++)
            T[(n0 + ty + i) * DD + k0 + tx] = tile[tx][ty + i];
    } else {
        int idx = (blk - 8192) * 256 + tid;
        if (idx < HH * 4095) {
            int h = idx / 4095, d = idx % 4095;
            int rel = d - 2047; // k - q
            int bucket = (rel > 0) ? 16 : 0;
            unsigned rr = (rel < 0) ? (unsigned)(-rel) : (unsigned)rel;
            int add;
            if (rr < 8) add = (int)rr;
            else {
                int e = 31 - __clz(rr);
                unsigned long long r2 = (unsigned long long)rr * (unsigned long long)rr;
                int f = 2 * e + ((r2 >= (2ull << (2 * e))) ? 1 : 0);
                add = 8 + (f - 6);
                if (add > 15) add = 15;
            }
            bucket += add;
            tab[h * 4095 + d] = rb[bucket * HH + h] * 1.44269504f;
        }
    }
}

// ---------------- fused QKV GEMM (r5-exact): C = A[4096][1024] * Wt[3072][1024]^T ----
__global__ __launch_bounds__(256) void gemm_qkv(
    const short* __restrict__ A, const short* __restrict__ Wt,
    short* __restrict__ Cq, short* __restrict__ Ck, short* __restrict__ Cvt) {
    const int K = 1024;
    __shared__ short As[128 * 32];
    __shared__ short Bs[128 * 32];
    int tid = threadIdx.x;
    int wave = tid >> 6, lane = tid & 63;
    int quad = lane >> 4, l16 = lane & 15;
    int m0 = blockIdx.y * 128, n0 = blockIdx.x * 128;

    int wm = (wave & 1) * 64, wn = (wave >> 1) * 64;
    int r0 = tid >> 2, c0 = (tid & 3) * 8;

    f32x4 acc[4][4];
#pragma unroll
    for (int i = 0; i < 4; i++)
#pragma unroll
        for (int j = 0; j < 4; j++) acc[i][j] = (f32x4){0.f, 0.f, 0.f, 0.f};

    for (int k0 = 0; k0 < K; k0 += 32) {
        __syncthreads();
        lds16(A + (size_t)(m0 + r0) * K + k0 + c0, As + wave * 512);
        lds16(A + (size_t)(m0 + 64 + r0) * K + k0 + c0, As + 2048 + wave * 512);
        lds16(Wt + (size_t)(n0 + r0) * K + k0 + c0, Bs + wave * 512);
        lds16(Wt + (size_t)(n0 + 64 + r0) * K + k0 + c0, Bs + 2048 + wave * 512);
        __syncthreads();
        bf16x8 af[4], bfr[4];
#pragma unroll
        for (int t = 0; t < 4; t++) {
            af[t] = *(const bf16x8*)(As + (wm + t * 16 + l16) * 32 + quad * 8);
            bfr[t] = *(const bf16x8*)(Bs + (wn + t * 16 + l16) * 32 + quad * 8);
        }
#pragma unroll
        for (int mt = 0; mt < 4; mt++)
#pragma unroll
            for (int nt = 0; nt < 4; nt++)
                acc[mt][nt] = mfma16(af[mt], bfr[nt], acc[mt][nt]);
    }

#pragma unroll
    for (int mt = 0; mt < 4; mt++) {
#pragma unroll
        for (int nt = 0; nt < 4; nt++) {
#pragma unroll
            for (int r = 0; r < 4; r++) {
                int gm = m0 + wm + mt * 16 + quad * 4 + r;
                int gn = n0 + wn + nt * 16 + l16;
                int b = gm >> 11, s = gm & 2047;
                int which = gn >> 10;       // wave-uniform per nt
                int h = (gn >> 6) & 15, dk = gn & 63;
                short bv = bf16b(acc[mt][nt][r]);
                if (which == 0)
                    Cq[(((size_t)(b * HH + h)) * SS + s) * DKK + dk] = bv;
                else if (which == 1)
                    Ck[(((size_t)(b * HH + h)) * SS + s) * DKK + dk] = bv;
                else
                    Cvt[(((size_t)(b * HH + h)) * DKK + dk) * SS + s] = bv;
            }
        }
    }
}

// ---------------- output projection (r5-exact): C[4096][1024] fp32 = A * WoT^T ------
__global__ __launch_bounds__(256) void gemm_out(
    const short* __restrict__ A, const short* __restrict__ Wt,
    float* __restrict__ Cout) {
    const int K = 1024, N = 1024;
    __shared__ short As[64 * 32];
    __shared__ short Bs[128 * 32];
    int tid = threadIdx.x;
    int wave = tid >> 6, lane = tid & 63;
    int quad = lane >> 4, l16 = lane & 15;
    int m0 = blockIdx.y * 64, n0 = blockIdx.x * 128;

    int wm = (wave & 1) * 32, wn = (wave >> 1) * 64;
    int r0 = tid >> 2, c0 = (tid & 3) * 8;

    f32x4 acc[2][4];
#pragma unroll
    for (int i = 0; i < 2; i++)
#pragma unroll
        for (int j = 0; j < 4; j++) acc[i][j] = (f32x4){0.f, 0.f, 0.f, 0.f};

    for (int k0 = 0; k0 < K; k0 += 32) {
        __syncthreads();
        lds16(A + (size_t)(m0 + r0) * K + k0 + c0, As + wave * 512);
        lds16(Wt + (size_t)(n0 + r0) * K + k0 + c0, Bs + wave * 512);
        lds16(Wt + (size_t)(n0 + 64 + r0) * K + k0 + c0, Bs + 2048 + wave * 512);
        __syncthreads();
        bf16x8 af[2], bfr[4];
#pragma unroll
        for (int t = 0; t < 2; t++)
            af[t] = *(const bf16x8*)(As + (wm + t * 16 + l16) * 32 + quad * 8);
#pragma unroll
        for (int t = 0; t < 4; t++)
            bfr[t] = *(const bf16x8*)(Bs + (wn + t * 16 + l16) * 32 + quad * 8);
#pragma unroll
        for (int mt = 0; mt < 2; mt++)
#pragma unroll
            for (int nt = 0; nt < 4; nt++)
                acc[mt][nt] = mfma16(af[mt], bfr[nt], acc[mt][nt]);
    }

#pragma unroll
    for (int mt = 0; mt < 2; mt++)
#pragma unroll
        for (int nt = 0; nt < 4; nt++)
#pragma unroll
            for (int r = 0; r < 4; r++) {
                int gm = m0 + wm + mt * 16 + quad * 4 + r;
                int gn = n0 + wn + nt * 16 + l16;
                Cout[(size_t)gm * N + gn] = acc[mt][nt][r];
            }
}

// ---------------- attention (r14: r11 structure + split-K for 2x TLP) ----------------
// r13 post-mortem: 1 wave/SIMD with in-wave ILP = latency-bound (77 us); r10:
// more waves but 2x per-work LDS cost (65 us); r11 best (59 us) but capped at
// 2048 waves (2/SIMD) with no pipe above 46% -> latency-bound.
// r14: identical per-wave structure to r11 (32 q/wave, same staging/swizzle/
// softmax), but split-K: 8-wave blocks, waves 0-3 do k[0,1024), waves 4-7 do
// k[1024,2048) for the same 128 q. 4096 waves -> 16/CU (4/SIMD), per-work pipe
// cost unchanged. LDS = 2 halves x (K+V dbuf) = 64 KB -> 2 blocks/CU. Epilogue:
// half-1 publishes partial o (reusing Ks as scratch, XOR bank swizzle) + row
// sums; half-0 merges, normalizes, stores. Combine ~2K cyc, negligible.
__global__ __launch_bounds__(512, 4) void attn(
    const short* __restrict__ Q, const short* __restrict__ Kmat,
    const short* __restrict__ Vt, const float* __restrict__ btab,
    short* __restrict__ O) {
    __shared__ short Ks[2][2][64 * 64];
    __shared__ short Vs[2][2][64 * 64];

    int tid = threadIdx.x;
    int wave = tid >> 6, lane = tid & 63;
    int w4 = wave & 3, half = wave >> 2;
    int el = lane & 31, hi = lane >> 5;
    int ex7 = el & 7;
    int bh = blockIdx.x;
    int h = bh & 15, b = bh >> 4;
    int q0b = blockIdx.y * 128;
    int q0w = q0b + w4 * 32;
    int ko = half * 1024;   // this wave's k-range: [ko, ko+1024)

    const short* Qb = Q + (size_t)bh * SS * DKK;
    const short* Kb = Kmat + (size_t)bh * SS * DKK;
    const short* Vb = Vt + (size_t)bh * DKK * SS;
    const float* bt = btab + h * 4095;

    float blo = bt[2047 - 128];
    float bhi = bt[2047 + 128];

    // staging (r11-exact per half): row kro, 16B slot, global slot XOR'd by row&7
    int tid2 = tid & 255;
    int kro = tid2 >> 3;
    int gk = (tid2 & 7) ^ (kro & 7);
    const short* Kg0 = Kb + (size_t)(ko + kro) * DKK + gk * 8;
    const short* Kg1 = Kb + (size_t)(ko + kro + 32) * DKK + gk * 8;
    const short* Vg0 = Vb + (size_t)kro * SS + ko + gk * 8;
    const short* Vg1 = Vb + (size_t)(kro + 32) * SS + ko + gk * 8;

    // Q B-fragments (held in registers)
    bf16x8 qB[4];
#pragma unroll
    for (int c = 0; c < 4; c++)
        qB[c] = *(const bf16x8*)(Qb + (size_t)(q0w + el) * DKK + c * 16 + hi * 8);

    f32x16 o0, o1;  // dk chunks [0,32) and [32,64); rows = q
#pragma unroll
    for (int i = 0; i < 16; i++) { o0[i] = 0.f; o1[i] = 0.f; }
    float ls0 = 0.f, ls1 = 0.f, ls2 = 0.f, ls3 = 0.f;

    int bq = 2047 - q0w - el;  // bias index base: d = bq + k

    lds16(Kg0, &Ks[half][0][w4 * 512]);
    lds16(Kg1, &Ks[half][0][2048 + w4 * 512]);
    lds16(Vg0, &Vs[half][0][w4 * 512]);
    lds16(Vg1, &Vs[half][0][2048 + w4 * 512]);

    int cur = 0;
    for (int kc2 = 0; kc2 < 1024; kc2 += 64) {
        __syncthreads();
        int kn2 = (kc2 + 64) & 1023;   // wraps within own half
        int nxt = cur ^ 1;
        lds16(Kg0 + (size_t)kn2 * DKK, &Ks[half][nxt][w4 * 512]);
        lds16(Kg1 + (size_t)kn2 * DKK, &Ks[half][nxt][2048 + w4 * 512]);
        lds16(Vg0 + kn2, &Vs[half][nxt][w4 * 512]);
        lds16(Vg1 + kn2, &Vs[half][nxt][2048 + w4 * 512]);

        const short* Ksc = &Ks[half][cur][0];
        const short* Vsc = &Vs[half][cur][0];

        // V B-fragments
        bf16x8 vf[4][2];
#pragma unroll
        for (int c4 = 0; c4 < 4; c4++)
#pragma unroll
            for (int m = 0; m < 2; m++)
                vf[c4][m] = *(const bf16x8*)(
                    Vsc + (m * 32 + el) * 64 + (((2 * c4 + hi) ^ ex7) * 8));

#pragma unroll
        for (int st = 0; st < 2; st++) {
            // QK^T for k-strip: D[k][q], lane col = q = el
            f32x16 acc;
#pragma unroll
            for (int i = 0; i < 16; i++) acc[i] = 0.f;
            __builtin_amdgcn_s_setprio(1);
#pragma unroll
            for (int c = 0; c < 4; c++) {
                bf16x8 kA = *(const bf16x8*)(
                    Ksc + (st * 32 + el) * 64 + (((2 * c + hi) ^ ex7) * 8));
                acc = mfma32(kA, qB[c], acc);
            }
            __builtin_amdgcn_s_setprio(0);

            int ks = ko + kc2 + st * 32;
            float br[16];
            if (ks > q0w - 159 && ks < q0w + 159) {
                // some |k-q| < 128 possible: table index safe in-range
#pragma unroll
                for (int r = 0; r < 16; r++)
                    br[r] = bt[bq + ks + ((r & 3) + 8 * (r >> 2) + 4 * hi)];
            } else {
                float bc = (ks <= q0w - 159) ? blo : bhi;
#pragma unroll
                for (int r = 0; r < 16; r++) br[r] = bc;
            }

            float p[16];
#pragma unroll
            for (int r = 0; r < 16; r++)
                p[r] = __builtin_amdgcn_exp2f(
                    fmaf(acc[r], 1.44269504f, br[r]));
#pragma unroll
            for (int r = 0; r < 16; r += 4) {
                ls0 += p[r]; ls1 += p[r + 1]; ls2 += p[r + 2]; ls3 += p[r + 3];
            }

            // pack own 16 p and swap halves -> PV A-fragments (T12)
            int A1 = cvtpk(p[0], p[1]),   A2 = cvtpk(p[2], p[3]);
            int B1 = cvtpk(p[4], p[5]),   B2 = cvtpk(p[6], p[7]);
            int C1 = cvtpk(p[8], p[9]),   C2 = cvtpk(p[10], p[11]);
            int D1 = cvtpk(p[12], p[13]), D2 = cvtpk(p[14], p[15]);
            swap32(A1, B1); swap32(A2, B2);
            swap32(C1, D1); swap32(C2, D2);
            bf16x8 pf0 = __builtin_bit_cast(bf16x8, (i32x4){A1, A2, B1, B2});
            bf16x8 pf1 = __builtin_bit_cast(bf16x8, (i32x4){C1, C2, D1, D2});

            // PV: o[q][dk] += P[q][k] * V[k][dk]
            __builtin_amdgcn_s_setprio(1);
            o0 = mfma32(pf0, vf[st * 2 + 0][0], o0);
            o1 = mfma32(pf0, vf[st * 2 + 0][1], o1);
            o0 = mfma32(pf1, vf[st * 2 + 1][0], o0);
            o1 = mfma32(pf1, vf[st * 2 + 1][1], o1);
            __builtin_amdgcn_s_setprio(0);
        }
        cur ^= 1;
    }
    __builtin_amdgcn_s_waitcnt(WAITCNT_VM0); // wrapped DMAs land before LDS reuse

    // per-wave partial row sum over its k-half: q = q0w + el
    float lsum = (ls0 + ls1) + (ls2 + ls3);
    float toth = lsum + __shfl_xor(lsum, 32);

    __syncthreads();   // all waves done with Ks/Vs tiles -> reuse as scratch

    float* Ob = (float*)&Ks[0][0][0];  // 32 KB: [w4][lane][32] XOR-swizzled
    float* Ls = (float*)&Vs[0][0][0];  // [0..127] tot1, [128..255] inv
    int ex5 = lane & 31;
    int obase = (w4 * 64 + lane) * 32;

    if (half == 1) {
        if (hi == 0) Ls[w4 * 32 + el] = toth;
#pragma unroll
        for (int j = 0; j < 16; j++) {
            Ob[obase + (j ^ ex5)] = o0[j];
            Ob[obase + ((16 + j) ^ ex5)] = o1[j];
        }
    }
    __syncthreads();
    if (half == 0) {
        float tot = toth + Ls[w4 * 32 + el];
        if (hi == 0) Ls[128 + w4 * 32 + el] = 1.f / tot;
        __asm__ __volatile__("" ::: "memory");
#pragma unroll
        for (int r = 0; r < 16; r++) {
            int qm = (r & 3) + 8 * (r >> 2) + 4 * hi;
            float iv = Ls[128 + w4 * 32 + qm];  // broadcast read
            float a0 = o0[r] + Ob[obase + (r ^ ex5)];
            float a1 = o1[r] + Ob[obase + ((16 + r) ^ ex5)];
            size_t base =
                ((size_t)(b * SS + q0w + qm)) * (HH * DKK) + h * DKK;
            O[base + el] = bf16b(a0 * iv);
            O[base + 32 + el] = bf16b(a1 * iv);
        }
    }
}

extern "C" void kernel_launch(void* const* d_in, const int* in_sizes, int n_in,
                              void* d_out, int out_size, void* d_ws, size_t ws_size,
                              hipStream_t stream) {
    const float* hs = (const float*)d_in[0];
    const float* Wq = (const float*)d_in[1];
    const float* Wk = (const float*)d_in[2];
    const float* Wv = (const float*)d_in[3];
    const float* Wo = (const float*)d_in[4];
    const float* rb = (const float*)d_in[5];
    float* out = (float*)d_out;

    char* ws = (char*)d_ws;
    size_t off = 0;
    auto alloc = [&](size_t bytes) -> void* {
        void* p = (void*)(ws + off);
        off += (bytes + 255) & ~(size_t)255;
        return p;
    };
    const size_t M = (size_t)BB * SS; // 4096
    short* hsb = (short*)alloc(M * DD * 2);
    // WqT/WkT/WvT MUST stay contiguous (2MB each, 256-aligned -> no padding):
    // gemm_qkv reads them as one [3072][1024] matrix.
    short* WqT = (short*)alloc((size_t)DD * DD * 2);
    short* WkT = (short*)alloc((size_t)DD * DD * 2);
    short* WvT = (short*)alloc((size_t)DD * DD * 2);
    short* WoT = (short*)alloc((size_t)DD * DD * 2);
    short* Qb  = (short*)alloc(M * DD * 2);
    short* Kb  = (short*)alloc(M * DD * 2);
    short* VTb = (short*)alloc(M * DD * 2);
    short* Ab  = (short*)alloc(M * DD * 2);
    float* btab = (float*)alloc((size_t)HH * 4095 * 4);

    prep<<<8448, 256, 0, stream>>>(hs, Wq, Wk, Wv, Wo, rb,
                                   hsb, WqT, WkT, WvT, WoT, btab);
    gemm_qkv<<<dim3(24, 32), 256, 0, stream>>>(hsb, WqT, Qb, Kb, VTb);
    attn<<<dim3(32, 16), 512, 0, stream>>>(Qb, Kb, VTb, btab, Ab);
    gemm_out<<<dim3(8, 64), 256, 0, stream>>>(Ab, WoT, out);
}

// Round 9
// 194.348 us; speedup vs baseline: 1.0985x; 1.0985x over previous
//
#include <hip/hip_runtime.h>

#define HH 16
#define DKK 64
#define SS 2048
#define BB 2
#define DD 1024

typedef __attribute__((ext_vector_type(4))) float f32x4;
typedef __attribute__((ext_vector_type(16))) float f32x16;
typedef __attribute__((ext_vector_type(8))) short bf16x8;
typedef __attribute__((ext_vector_type(4))) short s16x4;
typedef __attribute__((ext_vector_type(4))) int i32x4;

#define WAITCNT_VM0 0xF70  // vmcnt(0), ignore exp/lgkm

__device__ __forceinline__ short bf16b(float f) {
    union { float f; unsigned u; } x; x.f = f;
    unsigned r = (x.u + 0x7fffu + ((x.u >> 16) & 1u)) >> 16;
    return (short)r;
}

__device__ __forceinline__ f32x4 mfma16(bf16x8 a, bf16x8 b, f32x4 c) {
    return __builtin_amdgcn_mfma_f32_16x16x32_bf16(a, b, c, 0, 0, 0);
}

__device__ __forceinline__ f32x16 mfma32(bf16x8 a, bf16x8 b, f32x16 c) {
    return __builtin_amdgcn_mfma_f32_32x32x16_bf16(a, b, c, 0, 0, 0);
}

__device__ __forceinline__ void lds16(const short* g, short* l) {
    __builtin_amdgcn_global_load_lds(
        (const __attribute__((address_space(1))) void*)g,
        (__attribute__((address_space(3))) void*)l, 16, 0, 0);
}

// pack 2 f32 -> 1 dword of 2 bf16 (RNE)
__device__ __forceinline__ int cvtpk(float lo, float hi) {
    int r;
    asm("v_cvt_pk_bf16_f32 %0, %1, %2" : "=v"(r) : "v"(lo), "v"(hi));
    return r;
}

// swap a's upper 32 lanes with b's lower 32 lanes
__device__ __forceinline__ void swap32(int& a, int& b) {
    asm("v_permlane32_swap_b32 %0, %1" : "+v"(a), "+v"(b));
}

// ---------------- merged prologue: cast + transpose + bias in ONE launch ----------------
// blocks [0,4096): hs fp32->bf16; [4096,8192): weight transpose; [8192,8448): bias.
__global__ __launch_bounds__(256) void prep(
    const float* __restrict__ hs,
    const float* __restrict__ W0, const float* __restrict__ W1,
    const float* __restrict__ W2, const float* __restrict__ W3,
    const float* __restrict__ rb,
    short* __restrict__ hsb,
    short* __restrict__ T0, short* __restrict__ T1,
    short* __restrict__ T2, short* __restrict__ T3,
    float* __restrict__ tab) {
    __shared__ short tile[32][33];
    int blk = blockIdx.x, tid = threadIdx.x;
    if (blk < 4096) {
        int i = (blk * 256 + tid) * 4;
        f32x4 v = *(const f32x4*)(hs + i);
        s16x4 o;
        o.x = bf16b(v.x); o.y = bf16b(v.y); o.z = bf16b(v.z); o.w = bf16b(v.w);
        *(s16x4*)(hsb + i) = o;
    } else if (blk < 8192) {
        int t = blk - 4096;
        int z = t >> 10, r = t & 1023;
        int bx = r & 31, by = r >> 5;
        const float* W; short* T;
        switch (z) {
            case 0: W = W0; T = T0; break;
            case 1: W = W1; T = T1; break;
            case 2: W = W2; T = T2; break;
            default: W = W3; T = T3; break;
        }
        int n0 = bx * 32, k0 = by * 32;
        int tx = tid & 31, ty = (tid >> 5) * 4;
#pragma unroll
        for (int i = 0; i < 4; i++)
            tile[ty + i][tx] = bf16b(W[(k0 + ty + i) * DD + n0 + tx]);
        __syncthreads();
#pragma unroll
        for (int i = 0; i < 4; i++)
            T[(n0 + ty + i) * DD + k0 + tx] = tile[tx][ty + i];
    } else {
        int idx = (blk - 8192) * 256 + tid;
        if (idx < HH * 4095) {
            int h = idx / 4095, d = idx % 4095;
            int rel = d - 2047; // k - q
            int bucket = (rel > 0) ? 16 : 0;
            unsigned rr = (rel < 0) ? (unsigned)(-rel) : (unsigned)rel;
            int add;
            if (rr < 8) add = (int)rr;
            else {
                int e = 31 - __clz(rr);
                unsigned long long r2 = (unsigned long long)rr * (unsigned long long)rr;
                int f = 2 * e + ((r2 >= (2ull << (2 * e))) ? 1 : 0);
                add = 8 + (f - 6);
                if (add > 15) add = 15;
            }
            bucket += add;
            tab[h * 4095 + d] = rb[bucket * HH + h] * 1.44269504f;
        }
    }
}

// ---------------- fused QKV GEMM (r5-exact): C = A[4096][1024] * Wt[3072][1024]^T ----
__global__ __launch_bounds__(256) void gemm_qkv(
    const short* __restrict__ A, const short* __restrict__ Wt,
    short* __restrict__ Cq, short* __restrict__ Ck, short* __restrict__ Cvt) {
    const int K = 1024;
    __shared__ short As[128 * 32];
    __shared__ short Bs[128 * 32];
    int tid = threadIdx.x;
    int wave = tid >> 6, lane = tid & 63;
    int quad = lane >> 4, l16 = lane & 15;
    int m0 = blockIdx.y * 128, n0 = blockIdx.x * 128;

    int wm = (wave & 1) * 64, wn = (wave >> 1) * 64;
    int r0 = tid >> 2, c0 = (tid & 3) * 8;

    f32x4 acc[4][4];
#pragma unroll
    for (int i = 0; i < 4; i++)
#pragma unroll
        for (int j = 0; j < 4; j++) acc[i][j] = (f32x4){0.f, 0.f, 0.f, 0.f};

    for (int k0 = 0; k0 < K; k0 += 32) {
        __syncthreads();
        lds16(A + (size_t)(m0 + r0) * K + k0 + c0, As + wave * 512);
        lds16(A + (size_t)(m0 + 64 + r0) * K + k0 + c0, As + 2048 + wave * 512);
        lds16(Wt + (size_t)(n0 + r0) * K + k0 + c0, Bs + wave * 512);
        lds16(Wt + (size_t)(n0 + 64 + r0) * K + k0 + c0, Bs + 2048 + wave * 512);
        __syncthreads();
        bf16x8 af[4], bfr[4];
#pragma unroll
        for (int t = 0; t < 4; t++) {
            af[t] = *(const bf16x8*)(As + (wm + t * 16 + l16) * 32 + quad * 8);
            bfr[t] = *(const bf16x8*)(Bs + (wn + t * 16 + l16) * 32 + quad * 8);
        }
#pragma unroll
        for (int mt = 0; mt < 4; mt++)
#pragma unroll
            for (int nt = 0; nt < 4; nt++)
                acc[mt][nt] = mfma16(af[mt], bfr[nt], acc[mt][nt]);
    }

#pragma unroll
    for (int mt = 0; mt < 4; mt++) {
#pragma unroll
        for (int nt = 0; nt < 4; nt++) {
#pragma unroll
            for (int r = 0; r < 4; r++) {
                int gm = m0 + wm + mt * 16 + quad * 4 + r;
                int gn = n0 + wn + nt * 16 + l16;
                int b = gm >> 11, s = gm & 2047;
                int which = gn >> 10;       // wave-uniform per nt
                int h = (gn >> 6) & 15, dk = gn & 63;
                short bv = bf16b(acc[mt][nt][r]);
                if (which == 0)
                    Cq[(((size_t)(b * HH + h)) * SS + s) * DKK + dk] = bv;
                else if (which == 1)
                    Ck[(((size_t)(b * HH + h)) * SS + s) * DKK + dk] = bv;
                else
                    Cvt[(((size_t)(b * HH + h)) * DKK + dk) * SS + s] = bv;
            }
        }
    }
}

// ---------------- output projection (r5-exact): C[4096][1024] fp32 = A * WoT^T ------
__global__ __launch_bounds__(256) void gemm_out(
    const short* __restrict__ A, const short* __restrict__ Wt,
    float* __restrict__ Cout) {
    const int K = 1024, N = 1024;
    __shared__ short As[64 * 32];
    __shared__ short Bs[128 * 32];
    int tid = threadIdx.x;
    int wave = tid >> 6, lane = tid & 63;
    int quad = lane >> 4, l16 = lane & 15;
    int m0 = blockIdx.y * 64, n0 = blockIdx.x * 128;

    int wm = (wave & 1) * 32, wn = (wave >> 1) * 64;
    int r0 = tid >> 2, c0 = (tid & 3) * 8;

    f32x4 acc[2][4];
#pragma unroll
    for (int i = 0; i < 2; i++)
#pragma unroll
        for (int j = 0; j < 4; j++) acc[i][j] = (f32x4){0.f, 0.f, 0.f, 0.f};

    for (int k0 = 0; k0 < K; k0 += 32) {
        __syncthreads();
        lds16(A + (size_t)(m0 + r0) * K + k0 + c0, As + wave * 512);
        lds16(Wt + (size_t)(n0 + r0) * K + k0 + c0, Bs + wave * 512);
        lds16(Wt + (size_t)(n0 + 64 + r0) * K + k0 + c0, Bs + 2048 + wave * 512);
        __syncthreads();
        bf16x8 af[2], bfr[4];
#pragma unroll
        for (int t = 0; t < 2; t++)
            af[t] = *(const bf16x8*)(As + (wm + t * 16 + l16) * 32 + quad * 8);
#pragma unroll
        for (int t = 0; t < 4; t++)
            bfr[t] = *(const bf16x8*)(Bs + (wn + t * 16 + l16) * 32 + quad * 8);
#pragma unroll
        for (int mt = 0; mt < 2; mt++)
#pragma unroll
            for (int nt = 0; nt < 4; nt++)
                acc[mt][nt] = mfma16(af[mt], bfr[nt], acc[mt][nt]);
    }

#pragma unroll
    for (int mt = 0; mt < 2; mt++)
#pragma unroll
        for (int nt = 0; nt < 4; nt++)
#pragma unroll
            for (int r = 0; r < 4; r++) {
                int gm = m0 + wm + mt * 16 + quad * 4 + r;
                int gn = n0 + wn + nt * 16 + l16;
                Cout[(size_t)gm * N + gn] = acc[mt][nt][r];
            }
}

// ---------------- attention (r16: split-K in 256-thread blocks) ----------------------
// r15 (512-thread split-K) hit "container failed twice" twice in a row; no bug
// found in audit, but the 512-thread + __launch_bounds__(512,2) config is the
// only structurally new element — so the same theory is re-expressed in the
// r11-verified 256-thread shape:
//   - 4 waves/block: qw=wave&1 (64 q each -> 128 q/block), half=wave>>1
//     (k [0,1024) vs [1024,2048)). Grid (32,16)=512 blocks, 2048 waves,
//     8/CU = 2/SIMD (r11-equal TLP), 2 blocks/CU.
//   - per-work LDS reads HALVED vs r11: 16 ds_read_b128/iter feed 32 mfma32
//     (2 q-tiles share every K/V fragment).
//   - staging per half by its 2 waves (128 threads): 4 lds16 calls per 8KB
//     tile (16 rows each); slot-XOR invariant identical to r11 (16%8==0 so
//     row&7 is preserved; fragment-read XOR unchanged).
//   - __launch_bounds__(256,2) -> 256-reg cap (no r14-style spill).
// Epilogue: half-1 publishes partials into Ks(qt0)+Vs(qt1) scratch (r14-
// verified XOR scheme) + sums in Ls; half-0 merges/normalizes/stores.
__global__ __launch_bounds__(256, 2) void attn(
    const short* __restrict__ Q, const short* __restrict__ Kmat,
    const short* __restrict__ Vt, const float* __restrict__ btab,
    short* __restrict__ O) {
    __shared__ short Ks[2][2][64 * 64];
    __shared__ short Vs[2][2][64 * 64];
    __shared__ float Ls[2][256];  // [qt][0..127 tot(half1), 128..255 inv]

    int tid = threadIdx.x;
    int wave = tid >> 6, lane = tid & 63;
    int qw = wave & 1, half = wave >> 1;
    int el = lane & 31, hi = lane >> 5;
    int ex7 = el & 7;
    int bh = blockIdx.x;
    int h = bh & 15, b = bh >> 4;
    int q0b = blockIdx.y * 128;
    int q0w = q0b + qw * 64;   // this wave: q rows [q0w, q0w+64), 2 tiles of 32
    int ko = half * 1024;      // this wave: k range [ko, ko+1024)

    const short* Qb = Q + (size_t)bh * SS * DKK;
    const short* Kb = Kmat + (size_t)bh * SS * DKK;
    const short* Vb = Vt + (size_t)bh * DKK * SS;
    const float* bt = btab + h * 4095;

    float blo = bt[2047 - 128];
    float bhi = bt[2047 + 128];

    // staging: each half staged by its own 2 waves (128 threads), 4 calls/tile
    int tid_h = tid & 127;           // thread id within half
    int wh = tid_h >> 6;             // wave-in-half (0/1), wave-uniform
    int kro = tid_h >> 3;            // row 0..15 within 16-row call group
    int gk = (tid_h & 7) ^ (kro & 7);
    const short* Kg = Kb + (size_t)(ko + kro) * DKK + gk * 8;
    const short* Vg = Vb + (size_t)kro * SS + ko + gk * 8;

    auto stage = [&](int buf, int kofs) {
#pragma unroll
        for (int j = 0; j < 4; j++) {
            lds16(Kg + (size_t)(kofs + j * 16) * DKK,
                  &Ks[half][buf][j * 1024 + wh * 512]);
            lds16(Vg + kofs + (size_t)(j * 16) * SS,
                  &Vs[half][buf][j * 1024 + wh * 512]);
        }
    };

    // Q B-fragments for both q-tiles (held in registers)
    bf16x8 qB[2][4];
#pragma unroll
    for (int qt = 0; qt < 2; qt++)
#pragma unroll
        for (int c = 0; c < 4; c++)
            qB[qt][c] = *(const bf16x8*)(
                Qb + (size_t)(q0w + qt * 32 + el) * DKK + c * 16 + hi * 8);

    f32x16 o[2][2];  // [qtile][dk chunk 0/1]
#pragma unroll
    for (int qt = 0; qt < 2; qt++)
#pragma unroll
        for (int m = 0; m < 2; m++)
#pragma unroll
            for (int i = 0; i < 16; i++) o[qt][m][i] = 0.f;
    float ls[2][4];
#pragma unroll
    for (int qt = 0; qt < 2; qt++)
#pragma unroll
        for (int i = 0; i < 4; i++) ls[qt][i] = 0.f;

    int bq[2] = {2047 - q0w - el, 2047 - (q0w + 32) - el};

    stage(0, 0);

    int cur = 0;
    for (int kc2 = 0; kc2 < 1024; kc2 += 64) {
        __syncthreads();
        int kn2 = (kc2 + 64) & 1023;   // wraps within own half
        stage(cur ^ 1, kn2);

        const short* Ksc = &Ks[half][cur][0];
        const short* Vsc = &Vs[half][cur][0];

        // V B-fragments (shared by both strips and both q-tiles)
        bf16x8 vf[4][2];
#pragma unroll
        for (int c4 = 0; c4 < 4; c4++)
#pragma unroll
            for (int m = 0; m < 2; m++)
                vf[c4][m] = *(const bf16x8*)(
                    Vsc + (m * 32 + el) * 64 + (((2 * c4 + hi) ^ ex7) * 8));

#pragma unroll
        for (int st = 0; st < 2; st++) {
            // K A-fragments for this strip (shared by both q-tiles)
            bf16x8 kA[4];
#pragma unroll
            for (int c = 0; c < 4; c++)
                kA[c] = *(const bf16x8*)(
                    Ksc + (st * 32 + el) * 64 + (((2 * c + hi) ^ ex7) * 8));
            int ks = ko + kc2 + st * 32;

#pragma unroll
            for (int qt = 0; qt < 2; qt++) {
                int q0 = q0w + qt * 32;
                // QK^T: D[k][q], lane col = q = el
                f32x16 acc;
#pragma unroll
                for (int i = 0; i < 16; i++) acc[i] = 0.f;
                __builtin_amdgcn_s_setprio(1);
#pragma unroll
                for (int c = 0; c < 4; c++)
                    acc = mfma32(kA[c], qB[qt][c], acc);
                __builtin_amdgcn_s_setprio(0);

                float br[16];
                if (ks > q0 - 159 && ks < q0 + 159) {
                    // near-diagonal: table index in [1858,2236], safe
#pragma unroll
                    for (int r = 0; r < 16; r++)
                        br[r] = bt[bq[qt] + ks + ((r & 3) + 8 * (r >> 2) + 4 * hi)];
                } else {
                    float bc = (ks <= q0 - 159) ? blo : bhi;
#pragma unroll
                    for (int r = 0; r < 16; r++) br[r] = bc;
                }

                float p[16];
#pragma unroll
                for (int r = 0; r < 16; r++)
                    p[r] = __builtin_amdgcn_exp2f(
                        fmaf(acc[r], 1.44269504f, br[r]));
#pragma unroll
                for (int r = 0; r < 16; r += 4) {
                    ls[qt][0] += p[r];     ls[qt][1] += p[r + 1];
                    ls[qt][2] += p[r + 2]; ls[qt][3] += p[r + 3];
                }

                // pack own 16 p and swap halves -> PV A-fragments (T12)
                int A1 = cvtpk(p[0], p[1]),   A2 = cvtpk(p[2], p[3]);
                int B1 = cvtpk(p[4], p[5]),   B2 = cvtpk(p[6], p[7]);
                int C1 = cvtpk(p[8], p[9]),   C2 = cvtpk(p[10], p[11]);
                int D1 = cvtpk(p[12], p[13]), D2 = cvtpk(p[14], p[15]);
                swap32(A1, B1); swap32(A2, B2);
                swap32(C1, D1); swap32(C2, D2);
                bf16x8 pf0 = __builtin_bit_cast(bf16x8, (i32x4){A1, A2, B1, B2});
                bf16x8 pf1 = __builtin_bit_cast(bf16x8, (i32x4){C1, C2, D1, D2});

                // PV: o[q][dk] += P[q][k] * V[k][dk]
                __builtin_amdgcn_s_setprio(1);
                o[qt][0] = mfma32(pf0, vf[st * 2 + 0][0], o[qt][0]);
                o[qt][1] = mfma32(pf0, vf[st * 2 + 0][1], o[qt][1]);
                o[qt][0] = mfma32(pf1, vf[st * 2 + 1][0], o[qt][0]);
                o[qt][1] = mfma32(pf1, vf[st * 2 + 1][1], o[qt][1]);
                __builtin_amdgcn_s_setprio(0);
            }
        }
        cur ^= 1;
    }
    __builtin_amdgcn_s_waitcnt(WAITCNT_VM0); // wrapped DMAs land before LDS reuse

    // per-wave partial row sums over this k-half: q = q0 + el
    float toth[2];
#pragma unroll
    for (int qt = 0; qt < 2; qt++) {
        float lsum = (ls[qt][0] + ls[qt][1]) + (ls[qt][2] + ls[qt][3]);
        toth[qt] = lsum + __shfl_xor(lsum, 32);
    }

    __syncthreads();   // all waves done with Ks/Vs tiles -> reuse as scratch

    float* Ob0 = (float*)&Ks[0][0][0];  // 16 KB used: qt0 partials [qw][lane][32]
    float* Ob1 = (float*)&Vs[0][0][0];  // 16 KB used: qt1 partials
    int obase = (qw * 64 + lane) * 32;

    if (half == 1) {
        if (hi == 0) {
            Ls[0][qw * 32 + el] = toth[0];
            Ls[1][qw * 32 + el] = toth[1];
        }
#pragma unroll
        for (int j = 0; j < 16; j++) {
            Ob0[obase + (j ^ el)] = o[0][0][j];
            Ob0[obase + ((16 + j) ^ el)] = o[0][1][j];
            Ob1[obase + (j ^ el)] = o[1][0][j];
            Ob1[obase + ((16 + j) ^ el)] = o[1][1][j];
        }
    }
    __syncthreads();
    if (half == 0) {
#pragma unroll
        for (int qt = 0; qt < 2; qt++) {
            float tot = toth[qt] + Ls[qt][qw * 32 + el];
            if (hi == 0) Ls[qt][128 + qw * 32 + el] = 1.f / tot;
        }
        __asm__ __volatile__("" ::: "memory");
#pragma unroll
        for (int r = 0; r < 16; r++) {
            int qm = (r & 3) + 8 * (r >> 2) + 4 * hi;
#pragma unroll
            for (int qt = 0; qt < 2; qt++) {
                float iv = Ls[qt][128 + qw * 32 + qm];  // broadcast read
                const float* Obx = qt ? Ob1 : Ob0;
                float a0 = o[qt][0][r] + Obx[obase + (r ^ el)];
                float a1 = o[qt][1][r] + Obx[obase + ((16 + r) ^ el)];
                size_t base =
                    ((size_t)(b * SS + q0w + qt * 32 + qm)) * (HH * DKK) + h * DKK;
                O[base + el] = bf16b(a0 * iv);
                O[base + 32 + el] = bf16b(a1 * iv);
            }
        }
    }
}

extern "C" void kernel_launch(void* const* d_in, const int* in_sizes, int n_in,
                              void* d_out, int out_size, void* d_ws, size_t ws_size,
                              hipStream_t stream) {
    const float* hs = (const float*)d_in[0];
    const float* Wq = (const float*)d_in[1];
    const float* Wk = (const float*)d_in[2];
    const float* Wv = (const float*)d_in[3];
    const float* Wo = (const float*)d_in[4];
    const float* rb = (const float*)d_in[5];
    float* out = (float*)d_out;

    char* ws = (char*)d_ws;
    size_t off = 0;
    auto alloc = [&](size_t bytes) -> void* {
        void* p = (void*)(ws + off);
        off += (bytes + 255) & ~(size_t)255;
        return p;
    };
    const size_t M = (size_t)BB * SS; // 4096
    short* hsb = (short*)alloc(M * DD * 2);
    // WqT/WkT/WvT MUST stay contiguous (2MB each, 256-aligned -> no padding):
    // gemm_qkv reads them as one [3072][1024] matrix.
    short* WqT = (short*)alloc((size_t)DD * DD * 2);
    short* WkT = (short*)alloc((size_t)DD * DD * 2);
    short* WvT = (short*)alloc((size_t)DD * DD * 2);
    short* WoT = (short*)alloc((size_t)DD * DD * 2);
    short* Qb  = (short*)alloc(M * DD * 2);
    short* Kb  = (short*)alloc(M * DD * 2);
    short* VTb = (short*)alloc(M * DD * 2);
    short* Ab  = (short*)alloc(M * DD * 2);
    float* btab = (float*)alloc((size_t)HH * 4095 * 4);

    prep<<<8448, 256, 0, stream>>>(hs, Wq, Wk, Wv, Wo, rb,
                                   hsb, WqT, WkT, WvT, WoT, btab);
    gemm_qkv<<<dim3(24, 32), 256, 0, stream>>>(hsb, WqT, Qb, Kb, VTb);
    attn<<<dim3(32, 16), 256, 0, stream>>>(Qb, Kb, VTb, btab, Ab);
    gemm_out<<<dim3(8, 64), 256, 0, stream>>>(Ab, WoT, out);
}